// Round 6
// baseline (1172.556 us; speedup 1.0000x reference)
//
#include <hip/hip_runtime.h>
#include <cfloat>
#include <math.h>

#define NOBS   256
#define NY     50
#define NX     30
#define NITER  400
#define LRATE  0.05f
#define CSTR   260     // ep_t column stride (floats); %4==0 keeps float4 LDS loads 16B-aligned
#define THRANK 40      // theta tracks the rank-40 KEY -> C = 41 every valid iter (stable)
#define CAND   48      // candidate capacity for the local scan (C<=48 -> valid fast path)

__device__ __forceinline__ float rl_f(float x, int k) {
  return __int_as_float(__builtin_amdgcn_readlane(__float_as_int(x), k));
}
__device__ __forceinline__ int rl_i(int x, int k) {
  return __builtin_amdgcn_readlane(x, k);
}

// wave64 max: row_shr 1,2,4,8 + row_bcast 15,31; old=x keeps unwritten lanes at identity.
#define DPP_MAXSTEP(x, ctrl)                                                       \
  x = fmaxf(x, __int_as_float(__builtin_amdgcn_update_dpp(                         \
        __float_as_int(x), __float_as_int(x), (ctrl), 0xF, 0xF, false)))

// R6 (from R5=1071us): kill the A/B 2x replication. R5 counters: conflicts fixed (5.4e7->16k)
// but DS pipe (per-CU, shared by all waves) now carries ~55 ops/wave x 8 waves, half of it
// duplicated work (halves A/B compute identical fwd dots + rank scans). 256 threads = 1 obs
// per thread, 4 waves: DS ops/CU halve (~190), replicated VALU (fwd/scan/DPP/ballot) goes 1x.
// Forced per-wave growth: bwd 64 FMA + 16 b128 (was 32+8), proj split 13 steps (was 7).
// Barriers stay 3. Risk: 1 wave/SIMD exposes DS latency (no co-wave) -- falsifier is dur>=1071.
__global__ __launch_bounds__(256)
void dro_kernel(
    const float* __restrict__ X, const float* __restrict__ Y,
    const float* __restrict__ W, const float* __restrict__ Bb,
    const float* __restrict__ DLT, const float* __restrict__ GMM,
    float* __restrict__ out)
{
  __shared__ __align__(16) float smem[51 * CSTR];   // init: ep_t; after: overlays below
  __shared__ __align__(16) unsigned rrk[NOBS];      // full u32 keys (fallback scan)
  __shared__ __align__(16) unsigned ckey[2][128];   // parity-buffered dense candidates
  __shared__ __align__(16) float wmax4[4];
  __shared__ __align__(16) int   wtie4[4];
  __shared__ int cctr[2];                           // parity-buffered candidate counter
  __shared__ unsigned th_key;

  // Overlays (valid once ep_t is dead; disjoint; zs/cfs are WAVE-PRIVATE):
  float*  const zs  = smem;                  // [4][64] replicated z per wave
  float*  const rdx = smem + 256;            // [4][64] bwd partials (cross-wave, B2)
  float*  const cfs = smem + 512;            // [4][64] coef transpose (wave-private)
  float2* const pcx = (float2*)(smem + 768); // [4][64] proj (cs, ahead) (cross-wave, B3)

  const int tid  = threadIdx.x;     // 0..255 == owned observation
  const int lane = tid & 63;
  const int w4   = tid >> 6;        // wave 0..3 = obs quarter (obs base w4*64)
  const int t    = blockIdx.x;      // scenario

  const float delta = DLT[0];
  const float gamma = GMM[0];
  const float a     = fminf(delta * 0.5f, 255.0f / 256.0f);
  const float a256  = a * 256.0f;

  // ---- init: FULL residual row of owned obs in registers; stage ep column-major ----
  float er[NY];
  {
    float xr[NX];
    #pragma unroll
    for (int k = 0; k < NX; ++k) xr[k] = X[tid * NX + k];
    #pragma unroll
    for (int j = 0; j < NY; ++j) {               // W/B wave-uniform -> scalar loads
      float acc = Bb[j];
      #pragma unroll
      for (int k = 0; k < NX; ++k) acc = fmaf(xr[k], W[j * NX + k], acc);
      er[j] = Y[tid * NY + j] - acc;
      smem[j * CSTR + tid] = er[j];
    }
    smem[NY * CSTR + tid] = 1.0f;                // ones column -> c gradient
  }
  float yhl;                                     // y_hat[t][lane] per-lane copy
  {
    const int jr = (lane < NY) ? lane : 0;
    float acc = Bb[jr];
    #pragma unroll
    for (int k = 0; k < NX; ++k) acc = fmaf(X[t * NX + k], W[jr * NX + k], acc);
    yhl = acc;
    if (tid < NY) out[NOBS * NY + t * NY + tid] = acc;
  }
  if (tid == 0) { th_key = 0xFFFFFFFFu; cctr[0] = 0; cctr[1] = 0; }
  if (tid < CAND) { ckey[0][tid] = 0xFFFFFFFFu; ckey[1][tid] = 0xFFFFFFFFu; }
  __syncthreads();

  // epb: iteration-invariant backward slice in registers. Lane l: col min(l,50),
  // obs [w4*64, +64). coef of those obs -> cfs[w4*64 + q] (own wave's lanes).
  float epb[64];
  {
    const int colc = (lane < 51) ? lane : 50;
    const float* eb = &smem[colc * CSTR + w4 * 64];
    #pragma unroll
    for (int q = 0; q < 16; ++q) {
      const float4 e4 = *(const float4*)&eb[4 * q];
      epb[4*q+0] = e4.x; epb[4*q+1] = e4.y; epb[4*q+2] = e4.z; epb[4*q+3] = e4.w;
    }
  }
  __syncthreads();                               // ep_t dead -> overlays may be written

  float zv = (lane < NY) ? (1.0f / NY) : 0.0f;   // z one entry/lane, replicated per wave
  float cc = 0.0f;                               // c, replicated (bitwise identical)
  zs[w4 * 64 + lane] = zv;                       // wave-private z buffer (lanes>=50 -> 0)

  #pragma unroll 1
  for (int it = 0; it < NITER; ++it) {
    const int pp = it & 1;
    const unsigned thk = th_key;                 // last write 2 barriers ago -> fenced

    // ---- P0: fwd dot via wave-private LDS broadcast (13 b128, no rl chain) ----
    const float4* zp = (const float4*)&zs[w4 * 64];
    float d0 = 0.f, d1 = 0.f, d2 = 0.f, d3 = 0.f;
    #pragma unroll
    for (int jq = 0; jq < 12; ++jq) {
      const float4 z4 = zp[jq];
      d0 = fmaf(er[4*jq + 0], z4.x, d0);
      d1 = fmaf(er[4*jq + 1], z4.y, d1);
      d2 = fmaf(er[4*jq + 2], z4.z, d2);
      d3 = fmaf(er[4*jq + 3], z4.w, d3);
    }
    {
      const float4 z4 = zp[12];                  // z[48],z[49],0,0
      d0 = fmaf(er[48], z4.x, d0);
      d1 = fmaf(er[49], z4.y, d1);
    }
    const float u = ((d0 + d2) + (d1 + d3)) - cc;
    const float r = u * u;
    const unsigned key = __float_as_uint(r);     // non-negative f32 bits sort as u32

    float m = r;
    DPP_MAXSTEP(m, 0x111); DPP_MAXSTEP(m, 0x112);
    DPP_MAXSTEP(m, 0x114); DPP_MAXSTEP(m, 0x118);
    DPP_MAXSTEP(m, 0x142); DPP_MAXSTEP(m, 0x143);
    const float mw = rl_f(m, 63);                // wave (=quarter) max
    const int   wt = __popcll(__ballot(r == mw));

    const bool cond = (key <= thk);
    rrk[tid] = key;
    {
      const unsigned long long cmask = __ballot(cond);
      const int cpos = __popcll(cmask & ((1ull << lane) - 1ull));
      const int cq   = __popcll(cmask);
      int base = 0;
      if (lane == 0) base = atomicAdd(&cctr[pp], cq);   // dense cross-quarter offset
      base = rl_i(base, 0);
      const int pos = base + cpos;               // slot order nondeterministic; cnt is
      if (cond && pos < 128) ckey[pp][pos] = key;//   order-independent -> deterministic
      if (lane == 0) { wmax4[w4] = mw; wtie4[w4] = wt; }
    }
    __syncthreads();                             // B1: ckey/cctr/stats/rrk

    // ---- P1: local rank scan (broadcast LDS loads); coef; bwd partials ----
    const int Cu = __builtin_amdgcn_readfirstlane(cctr[pp]);
    if (tid == 0) cctr[pp ^ 1] = 0;              // consumed last iter; next write 2 bar. away
    if (tid < CAND) ckey[pp ^ 1][tid] = 0xFFFFFFFFu;    // sentinel prefill for next iter

    const float4 wm  = *(const float4*)wmax4;
    const int4   wtv = *(const int4*)wtie4;
    const float mx = fmaxf(fmaxf(wm.x, wm.y), fmaxf(wm.z, wm.w));
    const int   cm = (wm.x == mx ? wtv.x : 0) + (wm.y == mx ? wtv.y : 0)
                   + (wm.z == mx ? wtv.z : 0) + (wm.w == mx ? wtv.w : 0);
    const bool ismax = (r == mx);
    const bool valid = ((float)Cu >= a256) && (Cu <= CAND);

    int cnt;
    if (__builtin_expect(valid, 1)) {
      // candidates (keys<=thk) downward-closed -> candidate rank == exact global rank;
      // non-candidates get cnt=C>=a256 -> gfac=1/256 (exact). Sentinels never count.
      const uint4* cp = (const uint4*)&ckey[pp][0];     // uniform addr -> broadcast reads
      int n0 = 0, n1 = 0, n2 = 0, n3 = 0;
      #pragma unroll
      for (int jq = 0; jq < CAND / 4; ++jq) {
        const uint4 k4 = cp[jq];
        n0 += (k4.x < key) ? 1 : 0;
        n1 += (k4.y < key) ? 1 : 0;
        n2 += (k4.z < key) ? 1 : 0;
        n3 += (k4.w < key) ? 1 : 0;
      }
      cnt = (n0 + n1) + (n2 + n3);
    } else {                                     // iter 0 / drift: exact full scan
      const uint4* p = (const uint4*)rrk;
      int n0 = 0, n1 = 0, n2 = 0, n3 = 0;
      #pragma unroll 4
      for (int jq = 0; jq < 64; ++jq) {
        const uint4 k4 = p[jq];
        n0 += (k4.x < key) ? 1 : 0;
        n1 += (k4.y < key) ? 1 : 0;
        n2 += (k4.z < key) ? 1 : 0;
        n3 += (k4.w < key) ? 1 : 0;
      }
      cnt = (n0 + n1) + (n2 + n3);
    }
    // rank-40 key refresh: all cnt==40 threads share one key value (distinct keys can't
    // both have exactly 40 smaller) -> dup writes benign
    if (cnt == THRANK && (!valid || cond)) th_key = key;

    const float gfac  = fminf(fmaxf((float)cnt + 1.0f - a256, 0.0f), 1.0f) * (1.0f / 256.0f);
    const float g     = gfac + (ismax ? (a / (float)cm) : 0.0f);
    const float coefv = 2.0f * u * g;

    // backward: coef transpose via wave-private LDS (1 write + 16 broadcast b128)
    cfs[w4 * 64 + lane] = coefv;                 // in-order DS: reads below see this
    const float4* cfp = (const float4*)&cfs[w4 * 64];
    float q0 = 0.f, q1 = 0.f, q2 = 0.f, q3 = 0.f;
    #pragma unroll
    for (int q = 0; q < 16; ++q) {
      const float4 c4 = cfp[q];                  // coef of obs w4*64 + 4q .. +3
      q0 = fmaf(c4.x, epb[4 * q + 0], q0);
      q1 = fmaf(c4.y, epb[4 * q + 1], q1);
      q2 = fmaf(c4.z, epb[4 * q + 2], q2);
      q3 = fmaf(c4.w, epb[4 * q + 3], q3);
    }
    rdx[w4 * 64 + lane] = (q0 + q2) + (q1 + q3); // natural layout: conflict-free
    __syncthreads();                             // B2: rdx + th_key

    // ---- P2: z/c gradient step; 4-way wave-split projection scan ----
    const float r0 = rdx[lane],       r1 = rdx[64 + lane];
    const float r2 = rdx[128 + lane], r3 = rdx[192 + lane];
    const float s4 = (r0 + r1) + (r2 + r3);
    cc = cc + LRATE * rl_f(s4, NY);              // gc = -sum(coef); lane 50 = ones column
    const float gz = s4 - gamma * yhl;
    const float v  = zv - LRATE * gz;            // identical across waves

    int ahp = 0; float cs = 0.0f;                // desc-sort scan, index tie-break (ref order)
    if (w4 < 3) {
      const int kb = 13 * w4;                    // waves 0..2: k in [13w, 13w+13)
      #pragma unroll
      for (int s = 0; s < 13; ++s) {
        const float vk = rl_f(v, kb + s);
        const bool b = (vk > v) || (vk == v && (kb + s) > lane);
        ahp += b ? 1 : 0;
        cs  += b ? vk : 0.0f;
      }
    } else {                                     // wave 3: k in [39, 50)
      #pragma unroll
      for (int s = 0; s < 11; ++s) {
        const float vk = rl_f(v, 39 + s);
        const bool b = (vk > v) || (vk == v && (39 + s) > lane);
        ahp += b ? 1 : 0;
        cs  += b ? vk : 0.0f;
      }
    }
    pcx[w4 * 64 + lane] = make_float2(cs, (float)ahp);  // stride-2: 2-way conflict = free
    __syncthreads();                             // B3: pcx

    // ---- P3: combine partials -> tau; z update; publish z to wave-private buffer ----
    const float2 p0 = pcx[lane],       p1 = pcx[64 + lane];
    const float2 p2 = pcx[128 + lane], p3 = pcx[192 + lane];
    const float csF = ((p0.x + p1.x) + (p2.x + p3.x)) + v - 1.0f;
    const int aheadF = (int)((p0.y + p1.y) + (p2.y + p3.y));
    const bool pc = (lane < NY) && (v - csF / (float)(aheadF + 1) > 0.0f);
    const int rho = __popcll(__ballot(pc));      // >= 1 always
    const unsigned long long bsel = __ballot((lane < NY) && (aheadF == rho - 1));
    const int srcl = __ffsll(bsel) - 1;          // unique (ahp is a total order)
    const float tau =
        __int_as_float(__builtin_amdgcn_readlane(__float_as_int(csF), srcl)) / (float)rho;
    zv = (lane < NY) ? fmaxf(v - tau, 0.0f) : 0.0f;
    zs[w4 * 64 + lane] = zv;                     // wave-private; next-iter P0 reads (in-order)
  }

  if (w4 == 0 && lane < NY) out[t * NY + lane] = zv;

}

extern "C" void kernel_launch(void* const* d_in, const int* in_sizes, int n_in,
                              void* d_out, int out_size, void* d_ws, size_t ws_size,
                              hipStream_t stream) {
  (void)in_sizes; (void)n_in; (void)d_ws; (void)ws_size; (void)out_size;
  const float* X   = (const float*)d_in[0];
  const float* Y   = (const float*)d_in[1];
  const float* W   = (const float*)d_in[2];
  const float* B   = (const float*)d_in[3];
  const float* DLT = (const float*)d_in[4];
  const float* GMM = (const float*)d_in[5];
  float* out = (float*)d_out;
  hipLaunchKernelGGL(dro_kernel, dim3(NOBS), dim3(256), 0, stream,
                     X, Y, W, B, DLT, GMM, out);
}

// Round 7
// 1020.969 us; speedup vs baseline: 1.1485x; 1.1485x over previous
//
#include <hip/hip_runtime.h>
#include <cfloat>
#include <math.h>

#define NOBS   256
#define NY     50
#define NX     30
#define NITER  400
#define LRATE  0.05f
#define CSTR   260     // ep_t column stride (floats); %4==0 keeps float4 LDS loads 16B-aligned
#define THRANK 40      // theta tracks the rank-40 KEY -> C = 41 every valid iter (stable)
#define CAND   48      // candidate capacity for the local scan (C<=48 -> valid fast path)

__device__ __forceinline__ float rl_f(float x, int k) {
  return __int_as_float(__builtin_amdgcn_readlane(__float_as_int(x), k));
}
__device__ __forceinline__ int rl_i(int x, int k) {
  return __builtin_amdgcn_readlane(x, k);
}

// wave64 max: row_shr 1,2,4,8 + row_bcast 15,31; old=x keeps unwritten lanes at identity.
#define DPP_MAXSTEP(x, ctrl)                                                       \
  x = fmaxf(x, __int_as_float(__builtin_amdgcn_update_dpp(                         \
        __float_as_int(x), __float_as_int(x), (ctrl), 0xF, 0xF, false)))

// R7 (from R5=1071us best; R6's 4-wave test FAILED -> co-resident waves are needed to hide
// chain latency; binding resource = critical chain + barriers). This round shortens the chain:
//  - projection fully WAVE-LOCAL via the same wave-private LDS transpose as the fwd dot
//    (write v, 13 uniform b128 reads, 50-elem scan in-wave) -> B3 and the pcx exchange
//    round-trip are GONE. Barriers 3 -> 2.
//  - scan fast path is strict-> only (4 VALU/elem); exact whenever popc(bsel)==1
//    (proof: tied adjacent elements share the support predicate p*w>S_p-1 <=> (p+1)*w>S_p+w-1,
//    so ties never split rho; a tie AT the boundary forces popc(bsel)!=1 -> exact rescan).
//  - th_key prefetched into a register right after B2 (LDS read off the iter-start chain).
__global__ __launch_bounds__(512) __attribute__((amdgpu_waves_per_eu(2, 2)))
void dro_kernel(
    const float* __restrict__ X, const float* __restrict__ Y,
    const float* __restrict__ W, const float* __restrict__ Bb,
    const float* __restrict__ DLT, const float* __restrict__ GMM,
    float* __restrict__ out)
{
  __shared__ __align__(16) float smem[51 * CSTR];   // init: ep_t; after: overlays below
  __shared__ __align__(16) unsigned rrk[NOBS];      // full u32 keys (fallback scan)
  __shared__ __align__(16) unsigned ckey[2][128];   // parity-buffered dense candidates
  __shared__ __align__(16) float wmax4[4];
  __shared__ __align__(16) int   wtie4[4];
  __shared__ int cctr[2];                           // parity-buffered candidate counter
  __shared__ unsigned th_key;

  // Overlays (valid once ep_t is dead; disjoint; zs/cfs/vbf are WAVE-PRIVATE):
  float* const zs  = smem;                   // [8][64] replicated z per wave
  float* const rdx = smem + 512;             // [8][64] bwd partials (cross-wave, B2)
  float* const cfs = smem + 1024;            // [8][64] coef transpose (wave-private)
  float* const vbf = smem + 1536;            // [8][64] proj v transpose (wave-private)

  const int tid  = threadIdx.x;     // 0..511
  const int oid  = tid & 255;       // owned observation
  const int half = tid >> 8;        // bwd obs-slice half; A(0) writes shared state
  const int lane = tid & 63;
  const int w8   = tid >> 6;        // wave 0..7
  const int wsc  = w8 & 3;          // obs quarter (obs base wsc*64)
  const int t    = blockIdx.x;      // scenario

  const float delta = DLT[0];
  const float gamma = GMM[0];
  const float a     = fminf(delta * 0.5f, 255.0f / 256.0f);
  const float a256  = a * 256.0f;

  // ---- init: FULL residual row of owned obs in registers; stage ep column-major (A) ----
  float er[NY];
  {
    float xr[NX];
    #pragma unroll
    for (int k = 0; k < NX; ++k) xr[k] = X[oid * NX + k];
    #pragma unroll
    for (int j = 0; j < NY; ++j) {               // W/B wave-uniform -> scalar loads
      float acc = Bb[j];
      #pragma unroll
      for (int k = 0; k < NX; ++k) acc = fmaf(xr[k], W[j * NX + k], acc);
      er[j] = Y[oid * NY + j] - acc;
      if (half == 0) smem[j * CSTR + oid] = er[j];
    }
    if (half == 0) smem[NY * CSTR + oid] = 1.0f; // ones column -> c gradient
  }
  float yhl;                                     // y_hat[t][lane] per-lane copy
  {
    const int jr = (lane < NY) ? lane : 0;
    float acc = Bb[jr];
    #pragma unroll
    for (int k = 0; k < NX; ++k) acc = fmaf(X[t * NX + k], W[jr * NX + k], acc);
    yhl = acc;
    if (tid < NY) out[NOBS * NY + t * NY + tid] = acc;
  }
  if (tid == 0) { th_key = 0xFFFFFFFFu; cctr[0] = 0; cctr[1] = 0; }
  if (tid < CAND) { ckey[0][tid] = 0xFFFFFFFFu; ckey[1][tid] = 0xFFFFFFFFu; }
  __syncthreads();

  // epb: iteration-invariant backward slice in registers. Lane l: col min(l,50),
  // obs [wsc*64 + half*32, +32). coef of those obs -> cfs[w8*64 + half*32 + q].
  float epb[32];
  {
    const int colc = (lane < 51) ? lane : 50;
    const float* eb = &smem[colc * CSTR + wsc * 64 + half * 32];
    #pragma unroll
    for (int q = 0; q < 8; ++q) {
      const float4 e4 = *(const float4*)&eb[4 * q];
      epb[4*q+0] = e4.x; epb[4*q+1] = e4.y; epb[4*q+2] = e4.z; epb[4*q+3] = e4.w;
    }
  }
  __syncthreads();                               // ep_t dead -> overlays may be written

  float zv = (lane < NY) ? (1.0f / NY) : 0.0f;   // z one entry/lane, replicated per wave
  float cc = 0.0f;                               // c, replicated (bitwise identical)
  unsigned thk = 0xFFFFFFFFu;                    // loop-carried th_key copy (== LDS value)
  zs[w8 * 64 + lane] = zv;                       // wave-private z buffer (lanes>=50 -> 0)

  #pragma unroll 1
  for (int it = 0; it < NITER; ++it) {
    const int pp = it & 1;

    // ---- P0: fwd dot via wave-private LDS broadcast (13 b128, no rl chain) ----
    const float4* zp = (const float4*)&zs[w8 * 64];
    float d0 = 0.f, d1 = 0.f, d2 = 0.f, d3 = 0.f;
    #pragma unroll
    for (int jq = 0; jq < 12; ++jq) {
      const float4 z4 = zp[jq];
      d0 = fmaf(er[4*jq + 0], z4.x, d0);
      d1 = fmaf(er[4*jq + 1], z4.y, d1);
      d2 = fmaf(er[4*jq + 2], z4.z, d2);
      d3 = fmaf(er[4*jq + 3], z4.w, d3);
    }
    {
      const float4 z4 = zp[12];                  // z[48],z[49],0,0
      d0 = fmaf(er[48], z4.x, d0);
      d1 = fmaf(er[49], z4.y, d1);
    }
    const float u = ((d0 + d2) + (d1 + d3)) - cc;
    const float r = u * u;
    const unsigned key = __float_as_uint(r);     // non-negative f32 bits sort as u32

    float m = r;
    DPP_MAXSTEP(m, 0x111); DPP_MAXSTEP(m, 0x112);
    DPP_MAXSTEP(m, 0x114); DPP_MAXSTEP(m, 0x118);
    DPP_MAXSTEP(m, 0x142); DPP_MAXSTEP(m, 0x143);
    const float mw = rl_f(m, 63);                // wave (=quarter) max
    const int   wt = __popcll(__ballot(r == mw));

    const bool cond = (key <= thk);
    if (half == 0) {                             // A writes all shared state
      rrk[oid] = key;
      const unsigned long long cmask = __ballot(cond);
      const int cpos = __popcll(cmask & ((1ull << lane) - 1ull));
      const int cq   = __popcll(cmask);
      int base = 0;
      if (lane == 0) base = atomicAdd(&cctr[pp], cq);   // dense cross-quarter offset
      base = rl_i(base, 0);
      const int pos = base + cpos;               // slot order nondeterministic; cnt is
      if (cond && pos < 128) ckey[pp][pos] = key;//   order-independent -> deterministic
      if (lane == 0) { wmax4[wsc] = mw; wtie4[wsc] = wt; }
    }
    __syncthreads();                             // B1: ckey/cctr/stats/rrk

    // ---- P1: local rank scan (broadcast LDS loads); coef; bwd partials ----
    const int Cu = __builtin_amdgcn_readfirstlane(cctr[pp]);
    if (tid == 0) cctr[pp ^ 1] = 0;              // consumed last iter; next write 2 bar. away
    if (tid < CAND) ckey[pp ^ 1][tid] = 0xFFFFFFFFu;    // sentinel prefill for next iter

    const float4 wm  = *(const float4*)wmax4;
    const int4   wtv = *(const int4*)wtie4;
    const float mx = fmaxf(fmaxf(wm.x, wm.y), fmaxf(wm.z, wm.w));
    const int   cm = (wm.x == mx ? wtv.x : 0) + (wm.y == mx ? wtv.y : 0)
                   + (wm.z == mx ? wtv.z : 0) + (wm.w == mx ? wtv.w : 0);
    const bool ismax = (r == mx);
    const bool valid = ((float)Cu >= a256) && (Cu <= CAND);

    int cnt;
    if (__builtin_expect(valid, 1)) {
      // candidates (keys<=thk) downward-closed -> candidate rank == exact global rank;
      // non-candidates get cnt=C>=a256 -> gfac=1/256 (exact). Sentinels never count.
      const uint4* cp = (const uint4*)&ckey[pp][0];     // uniform addr -> broadcast reads
      int n0 = 0, n1 = 0, n2 = 0, n3 = 0;
      #pragma unroll
      for (int jq = 0; jq < CAND / 4; ++jq) {
        const uint4 k4 = cp[jq];
        n0 += (k4.x < key) ? 1 : 0;
        n1 += (k4.y < key) ? 1 : 0;
        n2 += (k4.z < key) ? 1 : 0;
        n3 += (k4.w < key) ? 1 : 0;
      }
      cnt = (n0 + n1) + (n2 + n3);
    } else {                                     // iter 0 / drift: exact full scan
      const uint4* p = (const uint4*)rrk;
      int n0 = 0, n1 = 0, n2 = 0, n3 = 0;
      #pragma unroll 4
      for (int jq = 0; jq < 64; ++jq) {
        const uint4 k4 = p[jq];
        n0 += (k4.x < key) ? 1 : 0;
        n1 += (k4.y < key) ? 1 : 0;
        n2 += (k4.z < key) ? 1 : 0;
        n3 += (k4.w < key) ? 1 : 0;
      }
      cnt = (n0 + n1) + (n2 + n3);
    }
    // rank-40 key refresh (unique when valid; dup writes of same value benign)
    if (cnt == THRANK && (!valid || cond)) th_key = key;

    const float gfac  = fminf(fmaxf((float)cnt + 1.0f - a256, 0.0f), 1.0f) * (1.0f / 256.0f);
    const float g     = gfac + (ismax ? (a / (float)cm) : 0.0f);
    const float coefv = 2.0f * u * g;

    // backward: coef transpose via wave-private LDS (1 write + 8 broadcast b128)
    cfs[w8 * 64 + lane] = coefv;                 // in-order DS: reads below see this
    const float4* cfp = (const float4*)&cfs[w8 * 64 + half * 32];
    float q0 = 0.f, q1 = 0.f, q2 = 0.f, q3 = 0.f;
    #pragma unroll
    for (int q = 0; q < 8; ++q) {
      const float4 c4 = cfp[q];                  // coef of obs wsc*64 + half*32 + 4q..+3
      q0 = fmaf(c4.x, epb[4 * q + 0], q0);
      q1 = fmaf(c4.y, epb[4 * q + 1], q1);
      q2 = fmaf(c4.z, epb[4 * q + 2], q2);
      q3 = fmaf(c4.w, epb[4 * q + 3], q3);
    }
    rdx[w8 * 64 + lane] = (q0 + q2) + (q1 + q3); // natural layout: conflict-free
    __syncthreads();                             // B2: rdx + th_key
    thk = th_key;                                // prefetch: final since P1; next write is
                                                 //   after next B1 -> WAR-safe
    // ---- P2: z/c gradient step; fully wave-local projection (no 3rd barrier) ----
    const float r0 = rdx[lane],       r1 = rdx[64 + lane];
    const float r2 = rdx[128 + lane], r3 = rdx[192 + lane];
    const float r4 = rdx[256 + lane], r5 = rdx[320 + lane];
    const float r6 = rdx[384 + lane], r7 = rdx[448 + lane];
    const float s4 = ((r0 + r1) + (r2 + r3)) + ((r4 + r5) + (r6 + r7));
    cc = cc + LRATE * rl_f(s4, NY);              // gc = -sum(coef); lane 50 = ones column
    const float gz = s4 - gamma * yhl;
    const float v  = zv - LRATE * gz;            // column form: lane j holds v_j

    vbf[w8 * 64 + lane] = v;                     // wave-private transpose (in-order DS)
    const float4* vp = (const float4*)&vbf[w8 * 64];

    int   ahp = 0;
    float cs0 = 0.f, cs1 = 0.f;
    #pragma unroll
    for (int jq = 0; jq < 12; ++jq) {            // fast scan: strict > only
      const float4 k4 = vp[jq];
      ahp += (k4.x > v) ? 1 : 0;  cs0 += (k4.x > v) ? k4.x : 0.f;
      ahp += (k4.y > v) ? 1 : 0;  cs1 += (k4.y > v) ? k4.y : 0.f;
      ahp += (k4.z > v) ? 1 : 0;  cs0 += (k4.z > v) ? k4.z : 0.f;
      ahp += (k4.w > v) ? 1 : 0;  cs1 += (k4.w > v) ? k4.w : 0.f;
    }
    {
      const float4 k4 = vp[12];                  // elements 48,49 (50,51 read, unused)
      ahp += (k4.x > v) ? 1 : 0;  cs0 += (k4.x > v) ? k4.x : 0.f;
      ahp += (k4.y > v) ? 1 : 0;  cs1 += (k4.y > v) ? k4.y : 0.f;
    }
    float csF = (cs0 + cs1) + v - 1.0f;
    bool  pc  = (lane < NY) && (v - csF / (float)(ahp + 1) > 0.0f);
    int   rho = __popcll(__ballot(pc));
    unsigned long long bsel = __ballot((lane < NY) && (ahp == rho - 1));
    if (__builtin_expect(__popcll(bsel) != 1, 0)) {
      // exact tie-break rescan (rare; only when the boundary element is tied).
      int ahx = 0; float cx0 = 0.f, cx1 = 0.f;
      #pragma unroll
      for (int jq = 0; jq < 12; ++jq) {
        const float4 k4 = vp[jq];
        const int k = 4 * jq;
        const bool b0 = (k4.x > v) || (k4.x == v && (k + 0) > lane);
        const bool b1 = (k4.y > v) || (k4.y == v && (k + 1) > lane);
        const bool b2 = (k4.z > v) || (k4.z == v && (k + 2) > lane);
        const bool b3 = (k4.w > v) || (k4.w == v && (k + 3) > lane);
        ahx += (b0 ? 1 : 0) + (b1 ? 1 : 0) + (b2 ? 1 : 0) + (b3 ? 1 : 0);
        cx0 += b0 ? k4.x : 0.f;  cx1 += b1 ? k4.y : 0.f;
        cx0 += b2 ? k4.z : 0.f;  cx1 += b3 ? k4.w : 0.f;
      }
      {
        const float4 k4 = vp[12];
        const bool b0 = (k4.x > v) || (k4.x == v && 48 > lane);
        const bool b1 = (k4.y > v) || (k4.y == v && 49 > lane);
        ahx += (b0 ? 1 : 0) + (b1 ? 1 : 0);
        cx0 += b0 ? k4.x : 0.f;  cx1 += b1 ? k4.y : 0.f;
      }
      ahp = ahx;
      csF = (cx0 + cx1) + v - 1.0f;
      pc  = (lane < NY) && (v - csF / (float)(ahp + 1) > 0.0f);
      rho = __popcll(__ballot(pc));
      bsel = __ballot((lane < NY) && (ahp == rho - 1));
    }
    const int srcl = __ffsll(bsel) - 1;          // unique (see proof in header comment)
    const float tau =
        __int_as_float(__builtin_amdgcn_readlane(__float_as_int(csF), srcl)) / (float)rho;
    zv = (lane < NY) ? fmaxf(v - tau, 0.0f) : 0.0f;
    zs[w8 * 64 + lane] = zv;                     // wave-private; next-iter P0 reads (in-order)
  }

  if (w8 == 0 && lane < NY) out[t * NY + lane] = zv;

}

extern "C" void kernel_launch(void* const* d_in, const int* in_sizes, int n_in,
                              void* d_out, int out_size, void* d_ws, size_t ws_size,
                              hipStream_t stream) {
  (void)in_sizes; (void)n_in; (void)d_ws; (void)ws_size; (void)out_size;
  const float* X   = (const float*)d_in[0];
  const float* Y   = (const float*)d_in[1];
  const float* W   = (const float*)d_in[2];
  const float* B   = (const float*)d_in[3];
  const float* DLT = (const float*)d_in[4];
  const float* GMM = (const float*)d_in[5];
  float* out = (float*)d_out;
  hipLaunchKernelGGL(dro_kernel, dim3(NOBS), dim3(512), 0, stream,
                     X, Y, W, B, DLT, GMM, out);
}

// Round 8
// 953.846 us; speedup vs baseline: 1.2293x; 1.0704x over previous
//
#include <hip/hip_runtime.h>
#include <cfloat>
#include <math.h>

#define NOBS   256
#define NY     50
#define NX     30
#define NITER  400
#define LRATE  0.05f
#define CSTR   260     // ep_t column stride (floats); %4==0 keeps float4 LDS loads 16B-aligned
#define THRANK 40      // theta tracks the rank-40 KEY -> C = 41 every valid iter (stable)
#define CAND   48      // candidate capacity for the local scan (C<=48 -> valid fast path)

__device__ __forceinline__ float rl_f(float x, int k) {
  return __int_as_float(__builtin_amdgcn_readlane(__float_as_int(x), k));
}
__device__ __forceinline__ int rl_i(int x, int k) {
  return __builtin_amdgcn_readlane(x, k);
}

// wave64 max: row_shr 1,2,4,8 + row_bcast 15,31; old=x keeps unwritten lanes at identity.
#define DPP_MAXSTEP(x, ctrl)                                                       \
  x = fmaxf(x, __int_as_float(__builtin_amdgcn_update_dpp(                         \
        __float_as_int(x), __float_as_int(x), (ctrl), 0xF, 0xF, false)))

// wave64 SUM step: old=0 (NOT old=x -- sum is not idempotent; unfilled lanes must add 0).
#define DPP_SUMSTEP(x, ctrl, rmask)                                                \
  x += __int_as_float(__builtin_amdgcn_update_dpp(                                 \
        0, __float_as_int(x), (ctrl), (rmask), 0xF, false))

__device__ __forceinline__ float wave_sum_bcast(float x) {
  // full 64-lane sum, result broadcast to all lanes (readlane 63)
  DPP_SUMSTEP(x, 0x111, 0xF);   // row_shr:1
  DPP_SUMSTEP(x, 0x112, 0xF);   // row_shr:2
  DPP_SUMSTEP(x, 0x114, 0xF);   // row_shr:4
  DPP_SUMSTEP(x, 0x118, 0xF);   // row_shr:8  -> lanes 15/31/47/63 hold row sums
  DPP_SUMSTEP(x, 0x142, 0xA);   // row_bcast:15, rows 1,3 -> lanes 31/63 accumulate
  DPP_SUMSTEP(x, 0x143, 0xC);   // row_bcast:31, rows 2,3 -> lane 63 = total
  return rl_f(x, 63);
}

// R8 (from R7=1021us): projection block (largest VALU region, ~220 VALU + 14 DS of 475/45)
// replaced by lane-parallel MICHELOT: v already sits one-elem-per-lane, so each pass is
// tau=(S-1)/n -> mask v>tau -> masked DPP wave-sum (~20 VALU), ~3-5 uniform passes, ZERO LDS.
// Fixed point == sort-formula output (KKT; R2 validated Michelot numerics end-to-end).
// vbf overlay + tie-rescan machinery deleted. Everything else byte-identical to R7.
__global__ __launch_bounds__(512) __attribute__((amdgpu_waves_per_eu(2, 2)))
void dro_kernel(
    const float* __restrict__ X, const float* __restrict__ Y,
    const float* __restrict__ W, const float* __restrict__ Bb,
    const float* __restrict__ DLT, const float* __restrict__ GMM,
    float* __restrict__ out)
{
  __shared__ __align__(16) float smem[51 * CSTR];   // init: ep_t; after: overlays below
  __shared__ __align__(16) unsigned rrk[NOBS];      // full u32 keys (fallback scan)
  __shared__ __align__(16) unsigned ckey[2][128];   // parity-buffered dense candidates
  __shared__ __align__(16) float wmax4[4];
  __shared__ __align__(16) int   wtie4[4];
  __shared__ int cctr[2];                           // parity-buffered candidate counter
  __shared__ unsigned th_key;

  // Overlays (valid once ep_t is dead; disjoint; zs/cfs are WAVE-PRIVATE):
  float* const zs  = smem;                   // [8][64] replicated z per wave
  float* const rdx = smem + 512;             // [8][64] bwd partials (cross-wave, B2)
  float* const cfs = smem + 1024;            // [8][64] coef transpose (wave-private)

  const int tid  = threadIdx.x;     // 0..511
  const int oid  = tid & 255;       // owned observation
  const int half = tid >> 8;        // bwd obs-slice half; A(0) writes shared state
  const int lane = tid & 63;
  const int w8   = tid >> 6;        // wave 0..7
  const int wsc  = w8 & 3;          // obs quarter (obs base wsc*64)
  const int t    = blockIdx.x;      // scenario

  const float delta = DLT[0];
  const float gamma = GMM[0];
  const float a     = fminf(delta * 0.5f, 255.0f / 256.0f);
  const float a256  = a * 256.0f;

  // ---- init: FULL residual row of owned obs in registers; stage ep column-major (A) ----
  float er[NY];
  {
    float xr[NX];
    #pragma unroll
    for (int k = 0; k < NX; ++k) xr[k] = X[oid * NX + k];
    #pragma unroll
    for (int j = 0; j < NY; ++j) {               // W/B wave-uniform -> scalar loads
      float acc = Bb[j];
      #pragma unroll
      for (int k = 0; k < NX; ++k) acc = fmaf(xr[k], W[j * NX + k], acc);
      er[j] = Y[oid * NY + j] - acc;
      if (half == 0) smem[j * CSTR + oid] = er[j];
    }
    if (half == 0) smem[NY * CSTR + oid] = 1.0f; // ones column -> c gradient
  }
  float yhl;                                     // y_hat[t][lane] per-lane copy
  {
    const int jr = (lane < NY) ? lane : 0;
    float acc = Bb[jr];
    #pragma unroll
    for (int k = 0; k < NX; ++k) acc = fmaf(X[t * NX + k], W[jr * NX + k], acc);
    yhl = acc;
    if (tid < NY) out[NOBS * NY + t * NY + tid] = acc;
  }
  if (tid == 0) { th_key = 0xFFFFFFFFu; cctr[0] = 0; cctr[1] = 0; }
  if (tid < CAND) { ckey[0][tid] = 0xFFFFFFFFu; ckey[1][tid] = 0xFFFFFFFFu; }
  __syncthreads();

  // epb: iteration-invariant backward slice in registers. Lane l: col min(l,50),
  // obs [wsc*64 + half*32, +32). coef of those obs -> cfs[w8*64 + half*32 + q].
  float epb[32];
  {
    const int colc = (lane < 51) ? lane : 50;
    const float* eb = &smem[colc * CSTR + wsc * 64 + half * 32];
    #pragma unroll
    for (int q = 0; q < 8; ++q) {
      const float4 e4 = *(const float4*)&eb[4 * q];
      epb[4*q+0] = e4.x; epb[4*q+1] = e4.y; epb[4*q+2] = e4.z; epb[4*q+3] = e4.w;
    }
  }
  __syncthreads();                               // ep_t dead -> overlays may be written

  float zv = (lane < NY) ? (1.0f / NY) : 0.0f;   // z one entry/lane, replicated per wave
  float cc = 0.0f;                               // c, replicated (bitwise identical)
  unsigned thk = 0xFFFFFFFFu;                    // loop-carried th_key copy (== LDS value)
  zs[w8 * 64 + lane] = zv;                       // wave-private z buffer (lanes>=50 -> 0)

  #pragma unroll 1
  for (int it = 0; it < NITER; ++it) {
    const int pp = it & 1;

    // ---- P0: fwd dot via wave-private LDS broadcast (13 b128, no rl chain) ----
    const float4* zp = (const float4*)&zs[w8 * 64];
    float d0 = 0.f, d1 = 0.f, d2 = 0.f, d3 = 0.f;
    #pragma unroll
    for (int jq = 0; jq < 12; ++jq) {
      const float4 z4 = zp[jq];
      d0 = fmaf(er[4*jq + 0], z4.x, d0);
      d1 = fmaf(er[4*jq + 1], z4.y, d1);
      d2 = fmaf(er[4*jq + 2], z4.z, d2);
      d3 = fmaf(er[4*jq + 3], z4.w, d3);
    }
    {
      const float4 z4 = zp[12];                  // z[48],z[49],0,0
      d0 = fmaf(er[48], z4.x, d0);
      d1 = fmaf(er[49], z4.y, d1);
    }
    const float u = ((d0 + d2) + (d1 + d3)) - cc;
    const float r = u * u;
    const unsigned key = __float_as_uint(r);     // non-negative f32 bits sort as u32

    float m = r;
    DPP_MAXSTEP(m, 0x111); DPP_MAXSTEP(m, 0x112);
    DPP_MAXSTEP(m, 0x114); DPP_MAXSTEP(m, 0x118);
    DPP_MAXSTEP(m, 0x142); DPP_MAXSTEP(m, 0x143);
    const float mw = rl_f(m, 63);                // wave (=quarter) max
    const int   wt = __popcll(__ballot(r == mw));

    const bool cond = (key <= thk);
    if (half == 0) {                             // A writes all shared state
      rrk[oid] = key;
      const unsigned long long cmask = __ballot(cond);
      const int cpos = __popcll(cmask & ((1ull << lane) - 1ull));
      const int cq   = __popcll(cmask);
      int base = 0;
      if (lane == 0) base = atomicAdd(&cctr[pp], cq);   // dense cross-quarter offset
      base = rl_i(base, 0);
      const int pos = base + cpos;               // slot order nondeterministic; cnt is
      if (cond && pos < 128) ckey[pp][pos] = key;//   order-independent -> deterministic
      if (lane == 0) { wmax4[wsc] = mw; wtie4[wsc] = wt; }
    }
    __syncthreads();                             // B1: ckey/cctr/stats/rrk

    // ---- P1: local rank scan (broadcast LDS loads); coef; bwd partials ----
    const int Cu = __builtin_amdgcn_readfirstlane(cctr[pp]);
    if (tid == 0) cctr[pp ^ 1] = 0;              // consumed last iter; next write 2 bar. away
    if (tid < CAND) ckey[pp ^ 1][tid] = 0xFFFFFFFFu;    // sentinel prefill for next iter

    const float4 wm  = *(const float4*)wmax4;
    const int4   wtv = *(const int4*)wtie4;
    const float mx = fmaxf(fmaxf(wm.x, wm.y), fmaxf(wm.z, wm.w));
    const int   cm = (wm.x == mx ? wtv.x : 0) + (wm.y == mx ? wtv.y : 0)
                   + (wm.z == mx ? wtv.z : 0) + (wm.w == mx ? wtv.w : 0);
    const bool ismax = (r == mx);
    const bool valid = ((float)Cu >= a256) && (Cu <= CAND);

    int cnt;
    if (__builtin_expect(valid, 1)) {
      // candidates (keys<=thk) downward-closed -> candidate rank == exact global rank;
      // non-candidates get cnt=C>=a256 -> gfac=1/256 (exact). Sentinels never count.
      const uint4* cp = (const uint4*)&ckey[pp][0];     // uniform addr -> broadcast reads
      int n0 = 0, n1 = 0, n2 = 0, n3 = 0;
      #pragma unroll
      for (int jq = 0; jq < CAND / 4; ++jq) {
        const uint4 k4 = cp[jq];
        n0 += (k4.x < key) ? 1 : 0;
        n1 += (k4.y < key) ? 1 : 0;
        n2 += (k4.z < key) ? 1 : 0;
        n3 += (k4.w < key) ? 1 : 0;
      }
      cnt = (n0 + n1) + (n2 + n3);
    } else {                                     // iter 0 / drift: exact full scan
      const uint4* p = (const uint4*)rrk;
      int n0 = 0, n1 = 0, n2 = 0, n3 = 0;
      #pragma unroll 4
      for (int jq = 0; jq < 64; ++jq) {
        const uint4 k4 = p[jq];
        n0 += (k4.x < key) ? 1 : 0;
        n1 += (k4.y < key) ? 1 : 0;
        n2 += (k4.z < key) ? 1 : 0;
        n3 += (k4.w < key) ? 1 : 0;
      }
      cnt = (n0 + n1) + (n2 + n3);
    }
    // rank-40 key refresh (unique when valid; dup writes of same value benign)
    if (cnt == THRANK && (!valid || cond)) th_key = key;

    const float gfac  = fminf(fmaxf((float)cnt + 1.0f - a256, 0.0f), 1.0f) * (1.0f / 256.0f);
    const float g     = gfac + (ismax ? (a / (float)cm) : 0.0f);
    const float coefv = 2.0f * u * g;

    // backward: coef transpose via wave-private LDS (1 write + 8 broadcast b128)
    cfs[w8 * 64 + lane] = coefv;                 // in-order DS: reads below see this
    const float4* cfp = (const float4*)&cfs[w8 * 64 + half * 32];
    float q0 = 0.f, q1 = 0.f, q2 = 0.f, q3 = 0.f;
    #pragma unroll
    for (int q = 0; q < 8; ++q) {
      const float4 c4 = cfp[q];                  // coef of obs wsc*64 + half*32 + 4q..+3
      q0 = fmaf(c4.x, epb[4 * q + 0], q0);
      q1 = fmaf(c4.y, epb[4 * q + 1], q1);
      q2 = fmaf(c4.z, epb[4 * q + 2], q2);
      q3 = fmaf(c4.w, epb[4 * q + 3], q3);
    }
    rdx[w8 * 64 + lane] = (q0 + q2) + (q1 + q3); // natural layout: conflict-free
    __syncthreads();                             // B2: rdx + th_key
    thk = th_key;                                // prefetch: final since P1; next write is
                                                 //   after next B1 -> WAR-safe
    // ---- P2: z/c gradient step; lane-parallel Michelot projection (0 LDS, ~4 passes) ----
    const float r0 = rdx[lane],       r1 = rdx[64 + lane];
    const float r2 = rdx[128 + lane], r3 = rdx[192 + lane];
    const float r4 = rdx[256 + lane], r5 = rdx[320 + lane];
    const float r6 = rdx[384 + lane], r7 = rdx[448 + lane];
    const float s4 = ((r0 + r1) + (r2 + r3)) + ((r4 + r5) + (r6 + r7));
    cc = cc + LRATE * rl_f(s4, NY);              // gc = -sum(coef); lane 50 = ones column
    const float gz = s4 - gamma * yhl;
    const float v  = zv - LRATE * gz;            // column form: lane j holds v_j

    // Michelot: support shrinks monotonically to the KKT fixed point (== sort formula).
    // All lanes/waves hold identical v -> branches uniform. n >= 1 guaranteed.
    bool inm = (lane < NY);
    float S  = wave_sum_bcast(inm ? v : 0.0f);
    int   n  = NY;
    float tau = 0.0f;
    #pragma unroll 1
    for (int pass = 0; pass < 32; ++pass) {
      tau = (S - 1.0f) / (float)n;
      const bool nin = inm && (v > tau);
      const int  nn  = __popcll(__ballot(nin));
      if (nn == n) break;                        // fixed point (uniform)
      S = wave_sum_bcast(nin ? v : 0.0f);
      n = nn;
      inm = nin;
    }
    zv = (lane < NY) ? fmaxf(v - tau, 0.0f) : 0.0f;
    zs[w8 * 64 + lane] = zv;                     // wave-private; next-iter P0 reads (in-order)
  }

  if (w8 == 0 && lane < NY) out[t * NY + lane] = zv;

}

extern "C" void kernel_launch(void* const* d_in, const int* in_sizes, int n_in,
                              void* d_out, int out_size, void* d_ws, size_t ws_size,
                              hipStream_t stream) {
  (void)in_sizes; (void)n_in; (void)d_ws; (void)ws_size; (void)out_size;
  const float* X   = (const float*)d_in[0];
  const float* Y   = (const float*)d_in[1];
  const float* W   = (const float*)d_in[2];
  const float* B   = (const float*)d_in[3];
  const float* DLT = (const float*)d_in[4];
  const float* GMM = (const float*)d_in[5];
  float* out = (float*)d_out;
  hipLaunchKernelGGL(dro_kernel, dim3(NOBS), dim3(512), 0, stream,
                     X, Y, W, B, DLT, GMM, out);
}

// Round 9
// 838.752 us; speedup vs baseline: 1.3980x; 1.1372x over previous
//
#include <hip/hip_runtime.h>
#include <cfloat>
#include <math.h>

#define NOBS   256
#define NY     50
#define NX     30
#define NITER  400
#define LRATE  0.05f
#define CSTR   260     // ep_t column stride (floats); %4==0 keeps float4 LDS loads 16B-aligned
#define THRANK 40      // theta tracks the rank-40 KEY -> C = 41 every valid iter (stable)
#define CAND   48      // candidate capacity for the local scan (C<=48 -> valid fast path)

typedef float f32x2 __attribute__((ext_vector_type(2)));

__device__ __forceinline__ float rl_f(float x, int k) {
  return __int_as_float(__builtin_amdgcn_readlane(__float_as_int(x), k));
}
__device__ __forceinline__ int rl_i(int x, int k) {
  return __builtin_amdgcn_readlane(x, k);
}

// wave64 max: row_shr 1,2,4,8 + row_bcast 15,31; old=x keeps unwritten lanes at identity.
#define DPP_MAXSTEP(x, ctrl)                                                       \
  x = fmaxf(x, __int_as_float(__builtin_amdgcn_update_dpp(                         \
        __float_as_int(x), __float_as_int(x), (ctrl), 0xF, 0xF, false)))

// wave64 SUM step: old=0 (NOT old=x -- sum is not idempotent; unfilled lanes must add 0).
#define DPP_SUMSTEP(x, ctrl, rmask)                                                \
  x += __int_as_float(__builtin_amdgcn_update_dpp(                                 \
        0, __float_as_int(x), (ctrl), (rmask), 0xF, false))

__device__ __forceinline__ float wave_sum_bcast(float x) {
  // full 64-lane sum, result broadcast to all lanes (readlane 63)
  DPP_SUMSTEP(x, 0x111, 0xF);   // row_shr:1
  DPP_SUMSTEP(x, 0x112, 0xF);   // row_shr:2
  DPP_SUMSTEP(x, 0x114, 0xF);   // row_shr:4
  DPP_SUMSTEP(x, 0x118, 0xF);   // row_shr:8  -> lanes 15/31/47/63 hold row sums
  DPP_SUMSTEP(x, 0x142, 0xA);   // row_bcast:15, rows 1,3 -> lanes 31/63 accumulate
  DPP_SUMSTEP(x, 0x143, 0xC);   // row_bcast:31, rows 2,3 -> lane 63 = total
  return rl_f(x, 63);
}

// R9 (from R8=954us): remaining time is serial-chain latency (refit alpha~1.2ns/instr ->
// issue no longer binding; VALUBusy 50%). Three chain/issue cuts:
//  (1) Michelot WARM-START from carried support {zv>0}: any (tau,A) fixed point with
//      A={v>tau}, tau=(S_A-1)/|A| satisfies sum(max(v-tau,0))=1 -> IS the projection
//      (f(tau) strictly decreasing). Ballot-equality convergence test (set, not count).
//      ~1 pass typical vs ~4. Cap 8 passes -> fall back to R8's shrink-from-full loop.
//  (2) tau division -> v_rcp_f32 * : ~20 cyc/pass off the chain; ~2ulp tau error, safe.
//  (3) fwd/bwd FMA packed via ext_vector f32x2 + elementwise_fma (v_pk_fma_f32);
//      accumulator lane mapping keeps rounding BITWISE identical to R8.
__global__ __launch_bounds__(512) __attribute__((amdgpu_waves_per_eu(2, 2)))
void dro_kernel(
    const float* __restrict__ X, const float* __restrict__ Y,
    const float* __restrict__ W, const float* __restrict__ Bb,
    const float* __restrict__ DLT, const float* __restrict__ GMM,
    float* __restrict__ out)
{
  __shared__ __align__(16) float smem[51 * CSTR];   // init: ep_t; after: overlays below
  __shared__ __align__(16) unsigned rrk[NOBS];      // full u32 keys (fallback scan)
  __shared__ __align__(16) unsigned ckey[2][128];   // parity-buffered dense candidates
  __shared__ __align__(16) float wmax4[4];
  __shared__ __align__(16) int   wtie4[4];
  __shared__ int cctr[2];                           // parity-buffered candidate counter
  __shared__ unsigned th_key;

  // Overlays (valid once ep_t is dead; disjoint; zs/cfs are WAVE-PRIVATE):
  float* const zs  = smem;                   // [8][64] replicated z per wave
  float* const rdx = smem + 512;             // [8][64] bwd partials (cross-wave, B2)
  float* const cfs = smem + 1024;            // [8][64] coef transpose (wave-private)

  const int tid  = threadIdx.x;     // 0..511
  const int oid  = tid & 255;       // owned observation
  const int half = tid >> 8;        // bwd obs-slice half; A(0) writes shared state
  const int lane = tid & 63;
  const int w8   = tid >> 6;        // wave 0..7
  const int wsc  = w8 & 3;          // obs quarter (obs base wsc*64)
  const int t    = blockIdx.x;      // scenario

  const float delta = DLT[0];
  const float gamma = GMM[0];
  const float a     = fminf(delta * 0.5f, 255.0f / 256.0f);
  const float a256  = a * 256.0f;

  // ---- init: FULL residual row of owned obs (packed pairs); stage ep column-major (A) ----
  f32x2 er2[25];                                 // er2[p] = {er[2p], er[2p+1]}
  {
    float xr[NX];
    #pragma unroll
    for (int k = 0; k < NX; ++k) xr[k] = X[oid * NX + k];
    #pragma unroll
    for (int j = 0; j < NY; ++j) {               // W/B wave-uniform -> scalar loads
      float acc = Bb[j];
      #pragma unroll
      for (int k = 0; k < NX; ++k) acc = fmaf(xr[k], W[j * NX + k], acc);
      const float e = Y[oid * NY + j] - acc;
      if (j & 1) er2[j >> 1].y = e; else er2[j >> 1].x = e;   // static (unrolled)
      if (half == 0) smem[j * CSTR + oid] = e;
    }
    if (half == 0) smem[NY * CSTR + oid] = 1.0f; // ones column -> c gradient
  }
  float yhl;                                     // y_hat[t][lane] per-lane copy
  {
    const int jr = (lane < NY) ? lane : 0;
    float acc = Bb[jr];
    #pragma unroll
    for (int k = 0; k < NX; ++k) acc = fmaf(X[t * NX + k], W[jr * NX + k], acc);
    yhl = acc;
    if (tid < NY) out[NOBS * NY + t * NY + tid] = acc;
  }
  if (tid == 0) { th_key = 0xFFFFFFFFu; cctr[0] = 0; cctr[1] = 0; }
  if (tid < CAND) { ckey[0][tid] = 0xFFFFFFFFu; ckey[1][tid] = 0xFFFFFFFFu; }
  __syncthreads();

  // epb: iteration-invariant backward slice (packed pairs). Lane l: col min(l,50),
  // obs [wsc*64 + half*32, +32). coef of those obs -> cfs[w8*64 + half*32 + q].
  f32x2 epb2[16];
  {
    const int colc = (lane < 51) ? lane : 50;
    const float* eb = &smem[colc * CSTR + wsc * 64 + half * 32];
    #pragma unroll
    for (int q = 0; q < 8; ++q) {
      const float4 e4 = *(const float4*)&eb[4 * q];
      epb2[2*q]   = (f32x2){e4.x, e4.y};
      epb2[2*q+1] = (f32x2){e4.z, e4.w};
    }
  }
  __syncthreads();                               // ep_t dead -> overlays may be written

  float zv = (lane < NY) ? (1.0f / NY) : 0.0f;   // z one entry/lane, replicated per wave
  float cc = 0.0f;                               // c, replicated (bitwise identical)
  unsigned thk = 0xFFFFFFFFu;                    // loop-carried th_key copy (== LDS value)
  zs[w8 * 64 + lane] = zv;                       // wave-private z buffer (lanes>=50 -> 0)

  #pragma unroll 1
  for (int it = 0; it < NITER; ++it) {
    const int pp = it & 1;

    // ---- P0: fwd dot via wave-private LDS broadcast; packed FMA (25 pk ops) ----
    const float4* zp = (const float4*)&zs[w8 * 64];
    f32x2 a01 = {0.f, 0.f}, a23 = {0.f, 0.f};    // lanes: {d0,d1}, {d2,d3} of R8
    #pragma unroll
    for (int jq = 0; jq < 12; ++jq) {
      const float4 z4 = zp[jq];
      a01 = __builtin_elementwise_fma(er2[2*jq],   (f32x2){z4.x, z4.y}, a01);
      a23 = __builtin_elementwise_fma(er2[2*jq+1], (f32x2){z4.z, z4.w}, a23);
    }
    {
      const float4 z4 = zp[12];                  // z[48],z[49],0,0
      a01 = __builtin_elementwise_fma(er2[24], (f32x2){z4.x, z4.y}, a01);
    }
    const float u = ((a01.x + a23.x) + (a01.y + a23.y)) - cc;  // == ((d0+d2)+(d1+d3))
    const float r = u * u;
    const unsigned key = __float_as_uint(r);     // non-negative f32 bits sort as u32

    float m = r;
    DPP_MAXSTEP(m, 0x111); DPP_MAXSTEP(m, 0x112);
    DPP_MAXSTEP(m, 0x114); DPP_MAXSTEP(m, 0x118);
    DPP_MAXSTEP(m, 0x142); DPP_MAXSTEP(m, 0x143);
    const float mw = rl_f(m, 63);                // wave (=quarter) max
    const int   wt = __popcll(__ballot(r == mw));

    const bool cond = (key <= thk);
    if (half == 0) {                             // A writes all shared state
      rrk[oid] = key;
      const unsigned long long cmask = __ballot(cond);
      const int cpos = __popcll(cmask & ((1ull << lane) - 1ull));
      const int cq   = __popcll(cmask);
      int base = 0;
      if (lane == 0) base = atomicAdd(&cctr[pp], cq);   // dense cross-quarter offset
      base = rl_i(base, 0);
      const int pos = base + cpos;               // slot order nondeterministic; cnt is
      if (cond && pos < 128) ckey[pp][pos] = key;//   order-independent -> deterministic
      if (lane == 0) { wmax4[wsc] = mw; wtie4[wsc] = wt; }
    }
    __syncthreads();                             // B1: ckey/cctr/stats/rrk

    // ---- P1: local rank scan (broadcast LDS loads); coef; bwd partials ----
    const int Cu = __builtin_amdgcn_readfirstlane(cctr[pp]);
    if (tid == 0) cctr[pp ^ 1] = 0;              // consumed last iter; next write 2 bar. away
    if (tid < CAND) ckey[pp ^ 1][tid] = 0xFFFFFFFFu;    // sentinel prefill for next iter

    const float4 wm  = *(const float4*)wmax4;
    const int4   wtv = *(const int4*)wtie4;
    const float mx = fmaxf(fmaxf(wm.x, wm.y), fmaxf(wm.z, wm.w));
    const int   cm = (wm.x == mx ? wtv.x : 0) + (wm.y == mx ? wtv.y : 0)
                   + (wm.z == mx ? wtv.z : 0) + (wm.w == mx ? wtv.w : 0);
    const bool ismax = (r == mx);
    const bool valid = ((float)Cu >= a256) && (Cu <= CAND);

    int cnt;
    if (__builtin_expect(valid, 1)) {
      // candidates (keys<=thk) downward-closed -> candidate rank == exact global rank;
      // non-candidates get cnt=C>=a256 -> gfac=1/256 (exact). Sentinels never count.
      const uint4* cp = (const uint4*)&ckey[pp][0];     // uniform addr -> broadcast reads
      int n0 = 0, n1 = 0, n2 = 0, n3 = 0;
      #pragma unroll
      for (int jq = 0; jq < CAND / 4; ++jq) {
        const uint4 k4 = cp[jq];
        n0 += (k4.x < key) ? 1 : 0;
        n1 += (k4.y < key) ? 1 : 0;
        n2 += (k4.z < key) ? 1 : 0;
        n3 += (k4.w < key) ? 1 : 0;
      }
      cnt = (n0 + n1) + (n2 + n3);
    } else {                                     // iter 0 / drift: exact full scan
      const uint4* p = (const uint4*)rrk;
      int n0 = 0, n1 = 0, n2 = 0, n3 = 0;
      #pragma unroll 4
      for (int jq = 0; jq < 64; ++jq) {
        const uint4 k4 = p[jq];
        n0 += (k4.x < key) ? 1 : 0;
        n1 += (k4.y < key) ? 1 : 0;
        n2 += (k4.z < key) ? 1 : 0;
        n3 += (k4.w < key) ? 1 : 0;
      }
      cnt = (n0 + n1) + (n2 + n3);
    }
    // rank-40 key refresh (unique when valid; dup writes of same value benign)
    if (cnt == THRANK && (!valid || cond)) th_key = key;

    const float gfac  = fminf(fmaxf((float)cnt + 1.0f - a256, 0.0f), 1.0f) * (1.0f / 256.0f);
    const float g     = gfac + (ismax ? (a / (float)cm) : 0.0f);
    const float coefv = 2.0f * u * g;

    // backward: coef transpose via wave-private LDS; packed FMA (16 pk ops)
    cfs[w8 * 64 + lane] = coefv;                 // in-order DS: reads below see this
    const float4* cfp = (const float4*)&cfs[w8 * 64 + half * 32];
    f32x2 qa = {0.f, 0.f}, qb = {0.f, 0.f};      // lanes: {q0,q1}, {q2,q3} of R8
    #pragma unroll
    for (int q = 0; q < 8; ++q) {
      const float4 c4 = cfp[q];                  // coef of obs wsc*64 + half*32 + 4q..+3
      qa = __builtin_elementwise_fma((f32x2){c4.x, c4.y}, epb2[2*q],   qa);
      qb = __builtin_elementwise_fma((f32x2){c4.z, c4.w}, epb2[2*q+1], qb);
    }
    rdx[w8 * 64 + lane] = (qa.x + qb.x) + (qa.y + qb.y);  // == (q0+q2)+(q1+q3)
    __syncthreads();                             // B2: rdx + th_key
    thk = th_key;                                // prefetch: final since P1; next write is
                                                 //   after next B1 -> WAR-safe
    // ---- P2: z/c gradient step; warm-started Michelot projection (0 LDS) ----
    const float r0 = rdx[lane],       r1 = rdx[64 + lane];
    const float r2 = rdx[128 + lane], r3 = rdx[192 + lane];
    const float r4 = rdx[256 + lane], r5 = rdx[320 + lane];
    const float r6 = rdx[384 + lane], r7 = rdx[448 + lane];
    const float s4 = ((r0 + r1) + (r2 + r3)) + ((r4 + r5) + (r6 + r7));
    cc = cc + LRATE * rl_f(s4, NY);              // gc = -sum(coef); lane 50 = ones column
    const float gz = s4 - gamma * yhl;
    const float v  = zv - LRATE * gz;            // column form: lane j holds v_j

    // Warm-start: seed support with carried {zv>0} (= fixed-point support of prev iter).
    // Any (tau, A={v>tau}) with tau=(S_A-1)/|A| IS the projection (f strictly decreasing)
    // -> ballot-equality convergence is exact. Cap 8 passes -> proven shrink-from-full.
    float tau = 0.0f;
    {
      bool cur = (lane < NY) && (zv > 0.0f);     // nonempty: sum(z)=1
      unsigned long long bal = __ballot(cur);
      int   n = __popcll(bal);
      float S = wave_sum_bcast(cur ? v : 0.0f);
      bool done = false;
      #pragma unroll 1
      for (int pass = 0; pass < 8; ++pass) {
        tau = (S - 1.0f) * __builtin_amdgcn_rcpf((float)n);
        const bool nxt = (lane < NY) && (v > tau);
        const unsigned long long nbal = __ballot(nxt);   // nonempty: max>mean>tau
        if (nbal == bal) { done = true; break; } // set equality -> fixed point (uniform)
        bal = nbal;
        n   = __popcll(nbal);
        S   = wave_sum_bcast(nxt ? v : 0.0f);
      }
      if (__builtin_expect(!done, 0)) {          // fallback: R8 monotone shrink-from-full
        bool inm = (lane < NY);
        float Sf = wave_sum_bcast(inm ? v : 0.0f);
        int   nf = NY;
        #pragma unroll 1
        for (int pass = 0; pass < 32; ++pass) {
          tau = (Sf - 1.0f) * __builtin_amdgcn_rcpf((float)nf);
          const bool nin = inm && (v > tau);
          const int  nn  = __popcll(__ballot(nin));
          if (nn == nf) break;
          Sf = wave_sum_bcast(nin ? v : 0.0f);
          nf = nn;
          inm = nin;
        }
      }
    }
    zv = (lane < NY) ? fmaxf(v - tau, 0.0f) : 0.0f;
    zs[w8 * 64 + lane] = zv;                     // wave-private; next-iter P0 reads (in-order)
  }

  if (w8 == 0 && lane < NY) out[t * NY + lane] = zv;

}

extern "C" void kernel_launch(void* const* d_in, const int* in_sizes, int n_in,
                              void* d_out, int out_size, void* d_ws, size_t ws_size,
                              hipStream_t stream) {
  (void)in_sizes; (void)n_in; (void)d_ws; (void)ws_size; (void)out_size;
  const float* X   = (const float*)d_in[0];
  const float* Y   = (const float*)d_in[1];
  const float* W   = (const float*)d_in[2];
  const float* B   = (const float*)d_in[3];
  const float* DLT = (const float*)d_in[4];
  const float* GMM = (const float*)d_in[5];
  float* out = (float*)d_out;
  hipLaunchKernelGGL(dro_kernel, dim3(NOBS), dim3(512), 0, stream,
                     X, Y, W, B, DLT, GMM, out);
}